// Round 1
// baseline (1137.234 us; speedup 1.0000x reference)
//
#include <hip/hip_runtime.h>
#include <cstdint>
#include <cstddef>

#define TSTEPS 500
#define BATCH  64
#define FEAT   256
#define HID    512
#define OUTD   128

// ---------------- workspace layout (bytes) ----------------
#define XPROJ_OFF   ((size_t)0)
#define XPROJ_BYTES ((size_t)TSTEPS*BATCH*HID*4)          // 65,536,000
#define WRECT_OFF   (XPROJ_OFF + XPROJ_BYTES)
#define WRECT_BYTES ((size_t)HID*HID*4)                   // 1,048,576
#define WOUTT_OFF   (WRECT_OFF + WRECT_BYTES)
#define WOUTT_BYTES ((size_t)HID*OUTD*4)                  // 262,144
#define LISTS_OFF   (WOUTT_OFF + WOUTT_BYTES)
#define LISTS_BYTES ((size_t)TSTEPS*BATCH*HID*2)          // 32,768,000
#define CNTS_OFF    (LISTS_OFF + LISTS_BYTES)
#define CNTS_BYTES  ((size_t)TSTEPS*BATCH*4)              // 128,000

// ---------------- prep: transpose w_rec (512x512) and w_out (128x512) ----------------
__global__ __launch_bounds__(256) void prep_kernel(const float* __restrict__ w_rec,
                                                   const float* __restrict__ w_out,
                                                   float* __restrict__ w_recT,
                                                   float* __restrict__ w_outT) {
    __shared__ float tile[32][33];
    int bid = blockIdx.x;
    const int tid = threadIdx.x;
    const float* src;
    float* dst;
    int scols, srows, tr, tc;
    if (bid < 256) {                  // w_rec: 512x512 -> 16x16 tiles of 32
        src = w_rec; dst = w_recT; srows = 512; scols = 512;
        tr = bid >> 4; tc = bid & 15;
    } else {                          // w_out: 128x512 -> 4x16 tiles of 32
        bid -= 256;
        src = w_out; dst = w_outT; srows = 128; scols = 512;
        tr = bid >> 4; tc = bid & 15;
    }
    const int c = tid & 31;
    const int r0 = tid >> 5;          // 0..7
#pragma unroll
    for (int p = 0; p < 4; ++p) {
        int r = p * 8 + r0;
        tile[r][c] = src[(size_t)(tr * 32 + r) * scols + tc * 32 + c];
    }
    __syncthreads();
#pragma unroll
    for (int p = 0; p < 4; ++p) {
        int r = p * 8 + r0;
        // dst is [scols][srows]; dst[tc*32+r][tr*32+c] = src[tr*32+c][tc*32+r]
        dst[(size_t)(tc * 32 + r) * srows + tr * 32 + c] = tile[c][r];
    }
}

// ---------------- x_proj GEMM: [32000x256] * [512x256]^T -> [32000x512] fp32 ----------------
// Tiles: BM=BN=128, BK=32, 256 threads, 8x8 micro-tile.
__global__ __launch_bounds__(256) void xproj_kernel(const float* __restrict__ x,
                                                    const float* __restrict__ w_in,
                                                    float* __restrict__ xp) {
    __shared__ float At[32][132];   // [k][m], rows 528B (16B aligned)
    __shared__ float Bt[32][132];   // [k][n]
    const int tid = threadIdx.x;
    const int bm = blockIdx.x % 250;
    const int bn = blockIdx.x / 250;
    const int m0 = bm * 128, n0 = bn * 128;
    const int tx = tid & 15, ty = tid >> 4;
    const int lr = tid >> 3;            // 0..31
    const int lc = (tid & 7) << 2;      // 0,4,...,28

    float acc[8][8];
#pragma unroll
    for (int i = 0; i < 8; ++i)
#pragma unroll
        for (int j = 0; j < 8; ++j) acc[i][j] = 0.f;

    for (int k0 = 0; k0 < FEAT; k0 += 32) {
#pragma unroll
        for (int rr = 0; rr < 128; rr += 32) {
            float4 av = *reinterpret_cast<const float4*>(x + (size_t)(m0 + lr + rr) * FEAT + k0 + lc);
            At[lc + 0][lr + rr] = av.x; At[lc + 1][lr + rr] = av.y;
            At[lc + 2][lr + rr] = av.z; At[lc + 3][lr + rr] = av.w;
            float4 bv = *reinterpret_cast<const float4*>(w_in + (size_t)(n0 + lr + rr) * FEAT + k0 + lc);
            Bt[lc + 0][lr + rr] = bv.x; Bt[lc + 1][lr + rr] = bv.y;
            Bt[lc + 2][lr + rr] = bv.z; Bt[lc + 3][lr + rr] = bv.w;
        }
        __syncthreads();
#pragma unroll
        for (int kk = 0; kk < 32; ++kk) {
            float a[8], bb[8];
            *reinterpret_cast<float4*>(&a[0]) = *reinterpret_cast<const float4*>(&At[kk][ty * 8]);
            *reinterpret_cast<float4*>(&a[4]) = *reinterpret_cast<const float4*>(&At[kk][ty * 8 + 4]);
            *reinterpret_cast<float4*>(&bb[0]) = *reinterpret_cast<const float4*>(&Bt[kk][tx * 8]);
            *reinterpret_cast<float4*>(&bb[4]) = *reinterpret_cast<const float4*>(&Bt[kk][tx * 8 + 4]);
#pragma unroll
            for (int i = 0; i < 8; ++i)
#pragma unroll
                for (int j = 0; j < 8; ++j)
                    acc[i][j] = fmaf(a[i], bb[j], acc[i][j]);
        }
        __syncthreads();
    }
#pragma unroll
    for (int i = 0; i < 8; ++i) {
        float* dst = xp + (size_t)(m0 + ty * 8 + i) * HID + n0 + tx * 8;
        float4 o0 = make_float4(acc[i][0], acc[i][1], acc[i][2], acc[i][3]);
        float4 o1 = make_float4(acc[i][4], acc[i][5], acc[i][6], acc[i][7]);
        *reinterpret_cast<float4*>(dst)     = o0;
        *reinterpret_cast<float4*>(dst + 4) = o1;
    }
}

// ---------------- recurrent LIF-AdEx scan: one block per batch element ----------------
__global__ __launch_bounds__(512) void scan_kernel(const float* __restrict__ xproj,
                                                   const float* __restrict__ wrecT,  // [h'][h]
                                                   unsigned short* __restrict__ glists,
                                                   int* __restrict__ gcnts,
                                                   float* __restrict__ st_out) {
    const int b = blockIdx.x;
    const int tid = threadIdx.x;       // h = tid
    const int lane = tid & 63;
    const int wv = tid >> 6;           // 0..7
    __shared__ unsigned long long zw[8];
    __shared__ unsigned short slist[HID];

    float v = 0.f, cur = 0.f, ad = 0.f, zf = 0.f;
    int cnt = 0;

    for (int t = 0; t < TSTEPS; ++t) {
        const float xp = xproj[((size_t)t * BATCH + b) * HID + tid];

        // recurrent input: sum of w_recT rows over previous-step spike list
        float r = 0.f;
        int s = 0;
        for (; s + 4 <= cnt; s += 4) {
            int h0 = slist[s + 0], h1 = slist[s + 1], h2 = slist[s + 2], h3 = slist[s + 3];
            float f0 = wrecT[(size_t)h0 * HID + tid];
            float f1 = wrecT[(size_t)h1 * HID + tid];
            float f2 = wrecT[(size_t)h2 * HID + tid];
            float f3 = wrecT[(size_t)h3 * HID + tid];
            r += (f0 + f1) + (f2 + f3);
        }
        for (; s < cnt; ++s) r += wrecT[(size_t)slist[s] * HID + tid];

        // element-wise LIF-AdEx update (mirrors reference expression forms)
        float vd = v + 0.1f * (((0.0f - v) + 0.5f * __expf(0.f) * 0.f + 0.f) ); // placeholder removed below
        vd = v + 0.1f * ((((0.0f - v) + 0.5f * expf((v - 1.0f) * 2.0f)) + cur) - ad);
        float id = cur - 0.2f * cur;
        float aD = ad + 0.002f * (4.0f * v - ad);
        bool z = (vd - 1.0f) > 0.0f;
        v  = z ? 0.0f : vd;
        cur = id + xp + r;
        ad = aD + (z ? 0.02f : 0.0f);
        zf = z ? 1.0f : 0.0f;

        unsigned long long m = __ballot(z);
        __syncthreads();               // everyone done reading slist/zw
        if (lane == 0) zw[wv] = m;
        __syncthreads();               // zw complete

        // build spike index list for next step (and for the output kernel)
        int c = 0, tot = 0;
#pragma unroll
        for (int ww = 0; ww < 8; ++ww) {
            int p = __popcll(zw[ww]);
            if (ww < wv) c += p;
            tot += p;
        }
        if (z) {
            int pos = c + __popcll(m & ((1ULL << lane) - 1ULL));
            slist[pos] = (unsigned short)tid;
        }
        cnt = tot;
        __syncthreads();               // slist complete

        if (tid < cnt) glists[((size_t)t * BATCH + b) * HID + tid] = slist[tid];
        if (tid == 0) gcnts[t * BATCH + b] = cnt;
    }

    // final states: z, v, i, a  each [64][512]
    const size_t base = (size_t)b * HID + tid;
    st_out[0 * (size_t)BATCH * HID + base] = zf;
    st_out[1 * (size_t)BATCH * HID + base] = v;
    st_out[2 * (size_t)BATCH * HID + base] = cur;
    st_out[3 * (size_t)BATCH * HID + base] = ad;
}

// ---------------- output projection + exponential filter ----------------
// grid: 4 t-chunks x 64 batch; 64-step halo (decay 0.7769^64 ~ 9e-8) makes chunks independent.
__global__ __launch_bounds__(128) void out_kernel(const unsigned short* __restrict__ lists,
                                                  const int* __restrict__ cnts,
                                                  const float* __restrict__ woutT,  // [h][o]
                                                  const float* __restrict__ b_out,
                                                  float* __restrict__ out) {
    const int bid = blockIdx.x;
    const int b = bid & 63;
    const int chunk = bid >> 6;
    const int o = threadIdx.x;
    const int t0 = chunk * 125;
    const int tstart = (t0 >= 64) ? (t0 - 64) : 0;
    const int tend = t0 + 125;
    const float bo = b_out[o];
    const float cf = 0.2231435511314f;
    float y = 0.f;
    for (int t = tstart; t < tend; ++t) {
        const unsigned short* lp = lists + ((size_t)t * BATCH + b) * HID;
        int cnt = cnts[t * BATCH + b];
        float lin = bo;
        int s = 0;
        for (; s + 4 <= cnt; s += 4) {
            int h0 = lp[s + 0], h1 = lp[s + 1], h2 = lp[s + 2], h3 = lp[s + 3];
            float f0 = woutT[h0 * OUTD + o];
            float f1 = woutT[h1 * OUTD + o];
            float f2 = woutT[h2 * OUTD + o];
            float f3 = woutT[h3 * OUTD + o];
            lin += (f0 + f1) + (f2 + f3);
        }
        for (; s < cnt; ++s) lin += woutT[lp[s] * OUTD + o];
        y = y + cf * (lin - y);
        if (t >= t0) out[((size_t)t * BATCH + b) * OUTD + o] = y;
    }
}

// ---------------- launcher ----------------
extern "C" void kernel_launch(void* const* d_in, const int* in_sizes, int n_in,
                              void* d_out, int out_size, void* d_ws, size_t ws_size,
                              hipStream_t stream) {
    const float* x     = (const float*)d_in[0];
    const float* w_in  = (const float*)d_in[1];
    const float* w_rec = (const float*)d_in[2];
    const float* w_out = (const float*)d_in[3];
    const float* b_out = (const float*)d_in[4];
    float* out = (float*)d_out;

    char* ws = (char*)d_ws;
    float* xproj          = (float*)(ws + XPROJ_OFF);
    float* wrecT          = (float*)(ws + WRECT_OFF);
    float* woutT          = (float*)(ws + WOUTT_OFF);
    unsigned short* lists = (unsigned short*)(ws + LISTS_OFF);
    int* cnts             = (int*)(ws + CNTS_OFF);
    float* st_out = out + (size_t)TSTEPS * BATCH * OUTD;

    prep_kernel<<<320, 256, 0, stream>>>(w_rec, w_out, wrecT, woutT);
    xproj_kernel<<<1000, 256, 0, stream>>>(x, w_in, xproj);
    scan_kernel<<<64, 512, 0, stream>>>(xproj, wrecT, lists, cnts, st_out);
    out_kernel<<<256, 128, 0, stream>>>(lists, cnts, woutT, b_out, out);
}